// Round 11
// baseline (412.655 us; speedup 1.0000x reference)
//
#include <hip/hip_runtime.h>
#include <math.h>

typedef unsigned short u16;
typedef unsigned int   u32;
typedef __attribute__((ext_vector_type(8))) short short8;
typedef __attribute__((ext_vector_type(4))) short short4v;
typedef __attribute__((ext_vector_type(4))) float float4v;
typedef __attribute__((ext_vector_type(2))) float float2v;
typedef __attribute__((ext_vector_type(2))) unsigned int u32x2;

#define DI __device__ __forceinline__

DI float b2f(u16 v){ return __uint_as_float(((u32)v) << 16); }
DI u16 f2b(float f){
  u32 u = __float_as_uint(f);
  u32 r = (u + 0x7fffu + ((u >> 16) & 1u)) >> 16;
  return (u16)r;
}
// Branchless gelu via A&S 7.1.26 erf (|eps| <= 1.5e-7, far below bf16 noise).
DI float fast_gelu(float x){
  float ax = fabsf(x) * 0.70710678118654752f;
  float t  = __builtin_amdgcn_rcpf(fmaf(0.3275911f, ax, 1.0f));
  float p  = t * (0.254829592f + t * (-0.284496736f + t * (1.421413741f +
             t * (-1.453152027f + t * 1.061405429f))));
  float e  = __expf(-ax * ax);
  float ea = fmaf(-p, e, 1.0f);
  float er = (x >= 0.f) ? ea : -ea;
  return 0.5f * x * (1.0f + er);
}

// packed dual-FP32 FMA (CDNA VOP3P, gfx90a+)
DI float2v pk_fma(float2v a, float2v b, float2v c){
  float2v d;
  asm("v_pk_fma_f32 %0, %1, %2, %3" : "=v"(d) : "v"(a), "v"(b), "v"(c));
  return d;
}
// pack two f32 -> (bf16 lo | bf16 hi), RNE (same rounding as f2b)
DI u32 cvt_pk_bf16(float lo, float hi){
  u32 r;
  asm("v_cvt_pk_bf16_f32 %0, %1, %2" : "=v"(r) : "v"(lo), "v"(hi));
  return r;
}

// Shapes: Bb=4, A=7, C=32, H=W=32, E=128, HEADS=4, d=32, L=N=224, K_tok=7168, HID=85
// x_lf flat: [196][32][32][32] f32, img=(b*49+u*7+v), elem = img*32768 + c*1024 + h*32 + w
// branch 0 (h): token l=(u,h), reduce k=(c, n=(v,w))
// branch 1 (v): token l=(v,w), reduce k=(c, n=(u,h))
//
// Verified MFMA recipe: mfma_f32_16x16x32_bf16, operands loaded as [row][k],
// row=lane&15, k=quad*8+j (one b128); D[m][n]: m=quad*4+reg, n=lane&15.
// R15: k1 split-K atomics removed. R16: fast_gelu; k4 fused into k45; k6 V-staging.
// R17: k7 epilogue -> LDS transpose + u32x2 wide stores; x2 rows padded to 256.
// R20: k6 i-tile 8->4. R21: k1 split-K 32 + wide staging. R22: k7/k3 re-grid (397us).
// R23 (this round):
//   k7: Bs LDS staging DELETED -- B-fragments read directly from aoB (459 KB,
//       L2-resident; ~205 MB aggregate L2 reads ~ 6us). LDS 80->17.4 KB, no
//       staging barrier -> ~5 blocks/CU.
//   k3: xnb staging deleted the same way (zero LDS, zero barriers).
//   k_prep = k_wprep + k8w_prep fused (4040 blocks). k9_fc folded into
//   k9_final prologue with bit-identical summation order; 2 launches removed.

// ---------------- k_prep: all weight f32 -> bf16 conversions ----------------
__global__ __launch_bounds__(256) void k_prep(const float* __restrict__ lw0,
    const float* __restrict__ lw1, const float* __restrict__ pw0,
    const float* __restrict__ pw1,
    const float* __restrict__ pin0, const float* __restrict__ pin1,
    const float* __restrict__ po0,  const float* __restrict__ po1,
    const float* __restrict__ qw0,  const float* __restrict__ qw1,
    u16* __restrict__ linwB, u16* __restrict__ projB,
    u16* __restrict__ pinB, u16* __restrict__ poB, u16* __restrict__ qkvwB)
{
  if (blockIdx.x < 3584) {
    int base = blockIdx.x * 1024 + threadIdx.x;   // 3,670,016 total
    #pragma unroll
    for (int r = 0; r < 4; ++r) {
      int i = base + 256 * r;
      if (i < 1835008) {
        const float* src = (i < 917504) ? lw0 : lw1;
        linwB[i] = f2b(src[i % 917504]);
      } else if (i < 3670016) {
        int j = i - 1835008;
        const float* src = (j < 917504) ? pw0 : pw1;
        projB[j] = f2b(src[j % 917504]);
      }
    }
  } else {
    int idx = (blockIdx.x - 3584) * 256 + threadIdx.x;   // 116736 total
    if (idx < 12288) {
      int cc = idx & 31;
      int r = (idx >> 5) % 96;
      int hb = (idx >> 5) / 96;       // br*2+half
      int br = hb >> 1, half = hb & 1;
      const float* p = br ? pin1 : pin0;
      pinB[idx] = (r < 85) ? f2b(p[(half * 85 + r) * 32 + cc]) : (u16)0;
    } else if (idx < 18432) {
      int j = idx - 12288;
      int r = j % 96;
      int t = j / 96;                 // br*32+cc
      int br = t >> 5, cc = t & 31;
      const float* p = br ? po1 : po0;
      poB[j] = (r < 85) ? f2b(p[cc * 85 + r]) : (u16)0;
    } else if (idx < 116736) {
      int j = idx - 18432;            // [br][384][128]
      int br = j / 49152, rest = j % 49152;
      qkvwB[j] = f2b((br ? qw1 : qw0)[rest]);
    }
  }
}

// ---------------- K1a (MFMA): token GEMM partials -> xqp[ks][bb][tok][e] ----------------
// R21: ks 0..31 (c = ks), 7 steps of 32 k (= one (v2 or u) row of 32 n).
// Wide staging: A float4 (2/thread/step), W short4 (4/thread/step).
__global__ __launch_bounds__(256) void k1_mfma(const float* __restrict__ xlf,
    const u16* __restrict__ linwB, float* __restrict__ xqp)
{
  __shared__ __align__(16) u16 Asb[64][40];
  __shared__ __align__(16) u16 Wsb[128][40];
  const int ks   = blockIdx.x;   // 0..31, channel c = ks
  const int mblk = blockIdx.y;   // 0..3
  const int bb   = blockIdx.z;   // br*4+b
  const int br = bb >> 2, b = bb & 3;
  const int tid = threadIdx.x;
  const int wid = tid >> 6, lane = tid & 63;
  const int quad = lane >> 4, r16 = lane & 15;
  const int m0s = mblk * 64 + wid * 16;
  const bool active = (m0s < 224);
  const u16* wsrc = linwB + br * 917504;
  const int c = ks;

  float4v acc[8];
  #pragma unroll
  for (int nt = 0; nt < 8; ++nt) acc[nt] = (float4v){0.f, 0.f, 0.f, 0.f};

  #pragma unroll 1
  for (int step = 0; step < 7; ++step) {
    const int k0 = ks * 224 + step * 32;
    // ---- A staging: 2 x float4 per thread ----
    #pragma unroll
    for (int r = 0; r < 2; ++r) {
      int idx = tid + 256 * r;           // < 512
      if (br == 0) {
        int ml = idx >> 3, kl4 = idx & 7;
        int l = mblk * 64 + ml;
        float4v v4 = {0.f, 0.f, 0.f, 0.f};
        if (l < 224) {
          int u = l >> 5, h = l & 31;    // v2 = step, w2 = kl4*4..+3 (contiguous)
          v4 = *(const float4v*)&xlf[(b * 49 + u * 7 + step) * 32768 + c * 1024 + h * 32 + kl4 * 4];
        }
        u32 lo = cvt_pk_bf16(v4[0], v4[1]);
        u32 hi = cvt_pk_bf16(v4[2], v4[3]);
        *(u32x2*)&Asb[ml][kl4 * 4] = (u32x2){lo, hi};
      } else {
        int ml4 = idx & 15, kl = idx >> 4;
        int ml0 = ml4 * 4;
        int l0 = mblk * 64 + ml0;
        float4v v4 = {0.f, 0.f, 0.f, 0.f};
        if (l0 < 224) {
          int v2 = l0 >> 5, w2 = l0 & 31; // u = step, h = kl; w2 quad contiguous
          v4 = *(const float4v*)&xlf[(b * 49 + step * 7 + v2) * 32768 + c * 1024 + kl * 32 + w2];
        }
        Asb[ml0 + 0][kl] = f2b(v4[0]);
        Asb[ml0 + 1][kl] = f2b(v4[1]);
        Asb[ml0 + 2][kl] = f2b(v4[2]);
        Asb[ml0 + 3][kl] = f2b(v4[3]);
      }
    }
    // ---- W staging: 4 x short4 per thread ----
    #pragma unroll
    for (int r = 0; r < 4; ++r) {
      int idx = tid + 256 * r;           // < 1024
      int e = idx >> 3, kl4 = idx & 7;
      *(short4v*)&Wsb[e][kl4 * 4] = *(const short4v*)&wsrc[e * 7168 + k0 + kl4 * 4];
    }
    __syncthreads();
    if (active) {
      short8 af = *(const short8*)&Asb[wid * 16 + r16][quad * 8];
      #pragma unroll
      for (int nt = 0; nt < 8; ++nt) {
        short8 bf = *(const short8*)&Wsb[nt * 16 + r16][quad * 8];
        acc[nt] = __builtin_amdgcn_mfma_f32_16x16x32_bf16(af, bf, acc[nt], 0, 0, 0);
      }
    }
    __syncthreads();
  }
  if (active) {
    float* outp = xqp + ks * 229376 + (bb * 224 + m0s) * 128;
    #pragma unroll
    for (int nt = 0; nt < 8; ++nt) {
      int e = nt * 16 + r16;
      #pragma unroll
      for (int reg = 0; reg < 4; ++reg) {
        int tok = quad * 4 + reg;
        outp[tok * 128 + e] = acc[nt][reg];
      }
    }
  }
}

// ---------------- K1b: reduce 32 partials + LayerNorm(E) -> xn bf16 [bb][tok][e] ----------------
__global__ __launch_bounds__(256) void k1b_ln(const float* __restrict__ xqp,
    const float* __restrict__ g0, const float* __restrict__ b0,
    const float* __restrict__ g1, const float* __restrict__ b1,
    u16* __restrict__ xn)
{
  const int tid = threadIdx.x;
  const int row = blockIdx.x * 16 + (tid >> 4);   // (bb*224+tok), 0..1791
  const int p = tid & 15;
  const int bb = row / 224;
  const int br = bb >> 2;
  const float* lg = br ? g1 : g0;
  const float* lb = br ? b1 : b0;
  const int e0 = p * 8;
  float4v a0 = {0.f,0.f,0.f,0.f}, a1 = {0.f,0.f,0.f,0.f};
  const float* src = xqp + row * 128 + e0;
  #pragma unroll
  for (int ks = 0; ks < 32; ++ks) {
    const float4v* sp = (const float4v*)(src + ks * 229376);
    a0 += sp[0];
    a1 += sp[1];
  }
  float s = 0.f, s2 = 0.f;
  #pragma unroll
  for (int j = 0; j < 4; ++j) {
    s  += a0[j] + a1[j];
    s2 += a0[j] * a0[j] + a1[j] * a1[j];
  }
  #pragma unroll
  for (int m = 8; m >= 1; m >>= 1) {
    s  += __shfl_xor(s, m);
    s2 += __shfl_xor(s2, m);
  }
  float mean = s * (1.f / 128.f);
  float var  = s2 * (1.f / 128.f) - mean * mean;
  float rs   = rsqrtf(fmaxf(var, 0.f) + 1e-6f);
  u16 o[8];
  #pragma unroll
  for (int j = 0; j < 4; ++j) {
    o[j]     = f2b((a0[j] - mean) * rs * lg[e0 + j]     + lb[e0 + j]);
    o[4 + j] = f2b((a1[j] - mean) * rs * lg[e0 + 4 + j] + lb[e0 + 4 + j]);
  }
  *(short8*)&xn[row * 128 + e0] = *(const short8*)o;
}

// ---------------- K3 (MFMA): qkv 1x1 on pre-LN'd xn -> qkvp[bb][384][224] ----------------
// R23: zero LDS -- B-fragments read directly from xn (L2-resident, 459 KB).
__global__ __launch_bounds__(256) void k3_mfma(const u16* __restrict__ xn,
    const u16* __restrict__ qkvwB, float* __restrict__ qkvp)
{
  const int mchunk = blockIdx.x;  // 0..5
  const int nh = blockIdx.y;      // 0..1 token half
  const int bb = blockIdx.z;
  const int br = bb >> 2;
  const int tid = threadIdx.x;
  const int wid = tid >> 6, lane = tid & 63;
  const int quad = lane >> 4, r16 = lane & 15;

  const int mtile = mchunk * 64 + wid * 16;   // < 384
  const u16* wsrc = qkvwB + br * 49152;
  const u16* bsrc = xn + (bb * 224 + nh * 112) * 128;
  float4v acc[7];
  #pragma unroll
  for (int nt = 0; nt < 7; ++nt) acc[nt] = (float4v){0.f, 0.f, 0.f, 0.f};
  #pragma unroll
  for (int k = 0; k < 4; ++k) {
    short8 af = *(const short8*)&wsrc[(mtile + r16) * 128 + k * 32 + quad * 8];
    #pragma unroll
    for (int nt = 0; nt < 7; ++nt) {
      short8 bf = *(const short8*)&bsrc[(nt * 16 + r16) * 128 + k * 32 + quad * 8];
      acc[nt] = __builtin_amdgcn_mfma_f32_16x16x32_bf16(af, bf, acc[nt], 0, 0, 0);
    }
  }
  #pragma unroll
  for (int nt = 0; nt < 7; ++nt) {
    int tok = nh * 112 + nt * 16 + r16;
    #pragma unroll
    for (int reg = 0; reg < 4; ++reg) {
      int o = mtile + quad * 4 + reg;
      qkvp[(bb * 384 + o) * 224 + tok] = acc[nt][reg];
    }
  }
}

// ---------------- K45: dw3x3 + head split + l2norm(q,k) -> qkvn[bb][sel][h][l][d] ----------------
// R17: split along v into 2 halves per (bb,sel,h) -> 192 blocks.
__global__ __launch_bounds__(256) void k45_dwheads(const float* __restrict__ qkvp,
    const float* __restrict__ dw0, const float* __restrict__ dw1,
    float* __restrict__ qkvn)
{
  __shared__ float ps[32][161];   // staged rows (up to 5 v-rows = 160 l)
  __shared__ float ts[32][137];   // post-conv (up to 4 v-rows = 128 l), odd stride
  __shared__ float scs[128];
  const int bid = blockIdx.x;          // 192 blocks
  const int half = bid & 1;
  const int rest = bid >> 1;           // bb*12 + sel*4 + h
  const int h = rest & 3;
  const int sel = (rest >> 2) % 3;
  const int bb = rest / 12;
  const int br = bb >> 2;
  const int tid = threadIdx.x;
  const int o0 = sel * 128 + h * 32;
  const float* src = qkvp + (bb * 384 + o0) * 224;
  const float* dwa = (br ? dw1 : dw0) + o0 * 9;
  const int vin0  = half ? 3 : 0;
  const int nin   = half ? 128 : 160;
  const int vout0 = half ? 4 : 0;
  const int nout  = half ? 96 : 128;
  const int lout0 = vout0 * 32;
  for (int idx = tid; idx < 32 * nin; idx += 256) {
    int d = idx / nin, l = idx - d * nin;
    ps[d][l] = src[d * 224 + vin0 * 32 + l];
  }
  __syncthreads();
  for (int idx = tid; idx < 32 * nout; idx += 256) {
    int d = idx / nout, lo = idx - d * nout;
    int l = lout0 + lo;
    int v = l >> 5, w = l & 31;
    const float* dww = dwa + d * 9;
    float acc = 0.f;
    #pragma unroll
    for (int dy = -1; dy <= 1; ++dy) {
      int vv = v + dy; if (vv < 0 || vv > 6) continue;
      int vloc = vv - vin0;
      #pragma unroll
      for (int dx = -1; dx <= 1; ++dx) {
        int ww = w + dx; if (ww < 0 || ww > 31) continue;
        acc += ps[d][vloc * 32 + ww] * dww[(dy + 1) * 3 + (dx + 1)];
      }
    }
    ts[d][lo] = acc;
  }
  __syncthreads();
  if (tid < nout) {
    float ss = 0.f;
    #pragma unroll 8
    for (int d = 0; d < 32; ++d) { float x = ts[d][tid]; ss += x * x; }
    scs[tid] = (sel < 2) ? (1.0f / fmaxf(sqrtf(ss), 1e-12f)) : 1.0f;
  }
  __syncthreads();
  float* dst = qkvn + ((bb * 3 + sel) * 4 + h) * 7168;
  for (int idx = tid; idx < 32 * nout; idx += 256) {
    int d = idx & 31, lo = idx >> 5;
    dst[(lout0 + lo) * 32 + d] = ts[d][lo] * scs[lo];
  }
}

// ---------------- K6: fused attention -> aoB[bb][tok][e] bf16 ----------------
// R20: i-tile 4 rows, grid 56x4x2 = 448 blocks. QK^T: 2 j/thread; softmax 16
// rows; PV: d(32) x head-pair(2) x row(4), all lanes active.
__global__ __launch_bounds__(256) void k6_attn(const float* __restrict__ qkvn,
    const float* __restrict__ tmp0, const float* __restrict__ tmp1,
    const float* __restrict__ ca0,  const float* __restrict__ ca1,
    u16* __restrict__ aoB)
{
  __shared__ float qs[16][33];      // (h*4+i, d)
  __shared__ float ks[128][33];     // (h*32+jj, d); reused as V tile in PV
  __shared__ float sS[16 * 228];    // (h*4+i)*228 + j
  __shared__ float mxs[16], rss[16];
  __shared__ float caf[32], tpf[4];
  const int it = blockIdx.x;        // 0..55 i-tile (4 rows)
  const int b = blockIdx.y, br = blockIdx.z;
  const int bb = br * 4 + b;
  const int tid = threadIdx.x;
  const float* tw = br ? tmp1 : tmp0;
  const float* cw = br ? ca1 : ca0;
  if (tid < 32) caf[tid] = cw[tid];
  if (tid < 4)  tpf[tid] = tw[tid];
  const int i0 = it * 4;
  const float* qb = qkvn + (bb * 3 + 0) * 4 * 7168;
  const float* kb = qkvn + (bb * 3 + 1) * 4 * 7168;
  const float* vb = qkvn + (bb * 3 + 2) * 4 * 7168;
  #pragma unroll
  for (int r = 0; r < 2; ++r) {
    int idx = tid + 256 * r;
    if (idx < 512) {
      int d = idx & 31, i = (idx >> 5) & 3, h = idx >> 7;
      qs[h * 4 + i][d] = qb[h * 7168 + (i0 + i) * 32 + d];
    }
  }
  __syncthreads();
  const int hC = tid >> 6, iC = (tid >> 4) & 3, jq = tid & 15;
  float qv[32];
  #pragma unroll
  for (int d2 = 0; d2 < 32; ++d2) qv[d2] = qs[hC * 4 + iC][d2];
  for (int jt = 0; jt < 7; ++jt) {
    __syncthreads();
    #pragma unroll
    for (int r = 0; r < 16; ++r) {
      int idx = tid + 256 * r;
      int d = idx & 31, jj = (idx >> 5) & 31, h = idx >> 10;
      ks[h * 32 + jj][d] = kb[h * 7168 + (jt * 32 + jj) * 32 + d];
    }
    __syncthreads();
    float a2[2] = {0.f, 0.f};
    for (int d = 0; d < 32; ++d) {
      #pragma unroll
      for (int r = 0; r < 2; ++r) a2[r] += qv[d] * ks[hC * 32 + jq + 16 * r][d];
    }
    #pragma unroll
    for (int r = 0; r < 2; ++r)
      sS[(hC * 4 + iC) * 228 + jt * 32 + jq + 16 * r] = a2[r] * tpf[hC];
  }
  __syncthreads();
  { // softmax stats per row (16 rows, 16 lanes each)
    int p = tid & 15, row = tid >> 4;
    float mx = -1e30f;
    for (int q = 0; q < 14; ++q) mx = fmaxf(mx, sS[row * 228 + p + 16 * q]);
    #pragma unroll
    for (int m = 8; m >= 1; m >>= 1) mx = fmaxf(mx, __shfl_xor(mx, m));
    float es = 0.f;
    for (int q = 0; q < 14; ++q) es += __expf(sS[row * 228 + p + 16 * q] - mx);
    #pragma unroll
    for (int m = 8; m >= 1; m >>= 1) es += __shfl_xor(es, m);
    if (p == 0) { mxs[row] = mx; rss[row] = 1.0f / es; }
  }
  __syncthreads();
  // attn = softmax*(1+scale)+shift, in place over sS (4 i-rows x 224 j)
  for (int q = 0; q < 4; ++q) {
    int pr = tid + 256 * q;
    if (pr < 896) {
      int i = pr / 224, j = pr % 224;
      float a1[4];
      #pragma unroll
      for (int hh = 0; hh < 4; ++hh) {
        float sv = sS[(hh * 4 + i) * 228 + j];
        float z = fmaxf(sv, 0.f); float z2 = z * z;
        a1[hh] = fast_gelu(z2) * z2;
      }
      #pragma unroll
      for (int hh = 0; hh < 4; ++hh) {
        float sc = 0.f, sh = 0.f;
        #pragma unroll
        for (int k2 = 0; k2 < 4; ++k2) { sc += caf[hh * 4 + k2] * a1[k2]; sh += caf[(hh + 4) * 4 + k2] * a1[k2]; }
        int row = hh * 4 + i;
        float at = __expf(sS[row * 228 + j] - mxs[row]) * rss[row];
        sS[row * 228 + j] = at * (1.f + sc) + sh;
      }
    }
  }
  __syncthreads();
  { // PV with per-32-token V tiles staged in LDS (ks[] reused) -> aoB bf16
    int d = tid & 31, hpair = (tid >> 5) & 1, rg = tid >> 6;   // rg in [0,4)
    float acc[2] = {0.f, 0.f};
    for (int jt = 0; jt < 7; ++jt) {
      __syncthreads();
      #pragma unroll
      for (int r = 0; r < 16; ++r) {
        int idx = tid + 256 * r;
        int dd = idx & 31, jj = (idx >> 5) & 31, hh2 = idx >> 10;
        ks[hh2 * 32 + jj][dd] = vb[hh2 * 7168 + (jt * 32 + jj) * 32 + dd];
      }
      __syncthreads();
      for (int j = 0; j < 32; ++j) {
        #pragma unroll
        for (int c2 = 0; c2 < 2; ++c2) {
          int hh = hpair * 2 + c2;
          acc[c2] += sS[(hh * 4 + rg) * 228 + jt * 32 + j] * ks[hh * 32 + j][d];
        }
      }
    }
    #pragma unroll
    for (int c2 = 0; c2 < 2; ++c2) {
      int hh = hpair * 2 + c2;
      aoB[(bb * 224 + i0 + rg) * 128 + hh * 32 + d] = f2b(acc[c2]);
    }
  }
}

// ---------------- K7 (MFMA): proj GEMM + residual -> x2 (bf16, X2S=256 rows) ----------------
// R23: no Bs staging -- B-fragments read directly from aoB (L2-resident).
// LDS = Ts only (17,408 B). Epilogue unchanged (LDS transpose + u32x2 stores).
__global__ __launch_bounds__(256) void k7_mfma(const u16* __restrict__ aoB,
    const u16* __restrict__ projB, const float* __restrict__ xlf, u16* __restrict__ x2)
{
  __shared__ float Ts[64][68];    // 17,408 B
  const int mchunk = blockIdx.x;  // 0..27
  const int mi = blockIdx.y;      // 0..3
  const int bb = blockIdx.z;
  const int br = bb >> 2, b = bb & 3;
  const int tid = threadIdx.x;
  const int wid = tid >> 6, lane = tid & 63;
  const int quad = lane >> 4, r16 = lane & 15;
  const u16* asrc = projB + br * 917504;
  const u16* bsrc = aoB + bb * 224 * 128;
  const int mbase = mchunk * 256 + (wid * 4 + mi) * 16;
  float4v acc[14];
  #pragma unroll
  for (int nt = 0; nt < 14; ++nt) acc[nt] = (float4v){0.f, 0.f, 0.f, 0.f};
  #pragma unroll
  for (int k = 0; k < 4; ++k) {
    short8 af = *(const short8*)&asrc[(mbase + r16) * 128 + k * 32 + quad * 8];
    #pragma unroll
    for (int nt = 0; nt < 14; ++nt) {
      short8 bf = *(const short8*)&bsrc[(nt * 16 + r16) * 128 + k * 32 + quad * 8];
      acc[nt] = __builtin_amdgcn_mfma_f32_16x16x32_bf16(af, bf, acc[nt], 0, 0, 0);
    }
  }
  // transpose + wide store in 4 column rounds (l in [rd*64, rd*64+64) ; last 32)
  #pragma unroll
  for (int rd = 0; rd < 4; ++rd) {
    const int ntn = (rd < 3) ? 4 : 2;
    __syncthreads();
    #pragma unroll
    for (int t = 0; t < 4; ++t) {
      if (t < ntn) {
        #pragma unroll
        for (int reg = 0; reg < 4; ++reg)
          Ts[wid * 16 + quad * 4 + reg][t * 16 + r16] = acc[rd * 4 + t][reg];
      }
    }
    __syncthreads();
    const int nq = ntn * 4;          // l-quads per row this round
    #pragma unroll
    for (int pass = 0; pass < 4; ++pass) {
      int idx = tid + 256 * pass;
      if (idx < 64 * nq) {
        int rloc = idx / nq;         // 0..63
        int qc = idx - rloc * nq;
        int row = mchunk * 256 + (((rloc >> 4) * 4 + mi) << 4) + (rloc & 15);
        int c = row / 224, n = row - c * 224;
        int l = rd * 64 + qc * 4;
        float4v tv = *(const float4v*)&Ts[rloc][qc * 4];
        float r0v, r1v, r2v, r3v;
        if (br == 0) {
          int img = b * 49 + (l >> 5) * 7 + (n >> 5);
          const float* xp = xlf + img * 32768 + c * 1024 + (l & 31) * 32 + (n & 31);
          r0v = xp[0]; r1v = xp[32]; r2v = xp[64]; r3v = xp[96];
        } else {
          int img = b * 49 + (n >> 5) * 7 + (l >> 5);
          float4v xv = *(const float4v*)(xlf + img * 32768 + c * 1024 + (n & 31) * 32 + (l & 31));
          r0v = xv[0]; r1v = xv[1]; r2v = xv[2]; r3v = xv[3];
        }
        u32 lo = cvt_pk_bf16(tv[0] + r0v, tv[1] + r1v);
        u32 hi = cvt_pk_bf16(tv[2] + r2v, tv[3] + r3v);
        u16* dp = &x2[(((br * 896 + b * 224 + n) * 32 + c) << 8) + l];
        *(u32x2*)dp = (u32x2){lo, hi};
      }
    }
  }
}

// ---------------- K8 (MFMA): LN(C)+pin+dw3x3+gelu gate+pout+residual ----------------
// R14 structure: 6 chunks of 16 rows. Phase A: pin MFMA pair-tiles -> t12
// (cvt_pk_bf16 u32 writes), plus pipelined pout MFMA for chunk it-1.
// Phase B: sliding-window dw3x3 (3 ds_read_b32/col, v_pk_fma_f32 dual-ch).
// LDS 39,872 B -> 4 blocks/CU. R17 form: x2 row stride 256.
__global__ __launch_bounds__(256, 4) void k8_mfma(u16* x2,
    const float* __restrict__ lg0, const float* __restrict__ lb0,
    const float* __restrict__ lg1, const float* __restrict__ lb1,
    const float* __restrict__ dwa0, const float* __restrict__ dwa1,
    const u16* __restrict__ pinB, const u16* __restrict__ poB)
{
  __shared__ __align__(16) u16 xnb[224][36];   // 16,128 B
  __shared__ __align__(16) u32 t12[16][231];   // 14,784 B  (t1 lo | tg hi), col = v*33+w
  __shared__ __align__(16) u16 gsb[224][20];   // 8,960 B
  const int img = blockIdx.x;    // 0..895
  const int br  = blockIdx.y;
  const float* lg  = br ? lg1 : lg0;
  const float* lb  = br ? lb1 : lb0;
  const float* dww = br ? dwa1 : dwa0;
  const u16* pinBr = pinB + br * 2 * 96 * 32;
  const u16* poBr  = poB + br * 32 * 96;
  const int tid = threadIdx.x;
  const int wid = tid >> 6, lane = tid & 63;
  const int quad = lane >> 4, r16 = lane & 15;
  u16* src = x2 + (br * 896 + img) * 8192;

  if (tid < 224) {
    float xr[32];
    #pragma unroll
    for (int cc = 0; cc < 32; ++cc) xr[cc] = b2f(src[cc * 256 + tid]);
    float s = 0.f, s2 = 0.f;
    #pragma unroll
    for (int cc = 0; cc < 32; ++cc) { s += xr[cc]; s2 += xr[cc] * xr[cc]; }
    float mean = s * (1.f / 32.f);
    float var  = s2 * (1.f / 32.f) - mean * mean;
    float rs   = rsqrtf(fmaxf(var, 0.f) + 1e-6f);
    #pragma unroll
    for (int cc = 0; cc < 32; ++cc)
      xnb[tid][cc] = f2b((xr[cc] - mean) * rs * lg[cc] + lb[cc]);
  }
  __syncthreads();

  float4v acc[7];
  #pragma unroll
  for (int i = 0; i < 7; ++i) acc[i] = (float4v){0.f, 0.f, 0.f, 0.f};

  #pragma unroll 1
  for (int it = 0; it < 6; ++it) {
    const int r0 = it * 16;
    // ---- phase A: pin MFMA pair-tiles -> t12; pipelined pout for chunk it-1 ----
    #pragma unroll
    for (int ni = 0; ni < 4; ++ni) {
      int n = wid + 4 * ni;
      if (n < 14) {
        const int tok = n * 16 + r16;
        short8 bf;
        const u16* xp = &xnb[tok][quad * 8];
        ((short4v*)&bf)[0] = *(const short4v*)xp;
        ((short4v*)&bf)[1] = *(const short4v*)(xp + 4);
        short8 af0 = *(const short8*)&pinBr[((r0 + r16) << 5) + quad * 8];
        short8 af1 = *(const short8*)&pinBr[((96 + r0 + r16) << 5) + quad * 8];
        float4v d0 = __builtin_amdgcn_mfma_f32_16x16x32_bf16(af0, bf,
                       (float4v){0.f, 0.f, 0.f, 0.f}, 0, 0, 0);
        float4v d1 = __builtin_amdgcn_mfma_f32_16x16x32_bf16(af1, bf,
                       (float4v){0.f, 0.f, 0.f, 0.f}, 0, 0, 0);
        const int col = tok + (tok >> 5);     // v*33 + w
        #pragma unroll
        for (int reg = 0; reg < 4; ++reg)
          t12[quad * 4 + reg][col] = cvt_pk_bf16(d0[reg], d1[reg]);
      }
    }
    if (it > 0) {
      const int koff = (it - 1) * 16;
      #pragma unroll
      for (int i = 0; i < 7; ++i) {
        int u = wid + 4 * i;
        int mt = u / 14, n = u - mt * 14;
        short8 af = {}, bf = {};
        if (quad < 2) {
          af = *(const short8*)&poBr[(mt * 16 + r16) * 96 + koff + quad * 8];
          const u16* gp = &gsb[n * 16 + r16][quad * 8];
          ((short4v*)&bf)[0] = *(const short4v*)gp;
          ((short4v*)&bf)[1] = *(const short4v*)(gp + 4);
        }
        acc[i] = __builtin_amdgcn_mfma_f32_16x16x32_bf16(af, bf, acc[i], 0, 0, 0);
      }
    }
    __syncthreads();
    // ---- phase B: sliding-window dw3x3 + gelu gate -> gsb ----
    if (tid < 224) {
      const int rl = tid & 15;        // channel-in-chunk (k index for pout)
      const int v  = tid >> 5;        // 0..6
      const int wh = (tid >> 4) & 1;  // half of the w range
      const int r  = r0 + rl;
      float2v wp[9];
      if (r < 85) {
        const float* w1 = dww + r * 9;
        const float* w2 = dww + (85 + r) * 9;
        #pragma unroll
        for (int t = 0; t < 9; ++t) wp[t] = (float2v){w1[t], w2[t]};
      } else {
        #pragma unroll
        for (int t = 0; t < 9; ++t) wp[t] = (float2v){0.f, 0.f};
      }
      const u32* trow = &t12[rl][0];
      const int c0 = v * 33;
      const int base = wh << 4;
      const bool vok0 = (v > 0), vok2 = (v < 6);
      float2v accP = {0.f, 0.f}, accC = {0.f, 0.f}, accN = {0.f, 0.f};
      #pragma unroll
      for (int it2 = 0; it2 < 18; ++it2) {
        bool cok = true;
        if (it2 == 0)  cok = (wh == 1);
        if (it2 == 17) cok = (wh == 0);
        if (cok) {
          const int cw = base - 1 + it2;
          u32 p0 = vok0 ? trow[c0 - 33 + cw] : 0u;
          u32 p1 =        trow[c0 + cw];
          u32 p2 = vok2 ? trow[c0 + 33 + cw] : 0u;
          float2v x0 = {__uint_as_float(p0 << 16), __uint_as_float(p0 & 0xffff0000u)};
          float2v x1 = {__uint_as_float(p1 << 16), __uint_as_float(p1 & 0xffff0000u)};
          float2v x2v = {__uint_as_float(p2 << 16), __uint_as_float(p2 & 0xffff0000u)};
          accP = pk_fma(x0, wp[2], accP);
          accC = pk_fma(x0, wp[1], accC);
          accN = pk_fma(x0, wp[0], accN);
          accP = pk_fma(x1, wp[5], accP);
          accC = pk_fma(x1, wp[4], accC);
          accN = pk_fma(x1, wp[3], accN);
          accP = pk_fma(x2v, wp[8], accP);
          accC = pk_fma(x2v, wp[7], accC);
          accN = pk_fma(x2v, wp[6], accN);
        }
        if (it2 >= 2) {
          float g = fast_gelu(accP[0]) * accP[1];
          gsb[(v << 5) + base + (it2 - 2)][rl] = f2b(g);
        }
        accP = accC; accC = accN; accN = (float2v){0.f, 0.f};
      }
    }
    __syncthreads();
  }
  { // trailing pout for chunk 5
    const int koff = 80;
    #pragma unroll
    for (int i = 0; i < 7; ++i) {
      int u = wid + 4 * i;
      int mt = u / 14, n = u - mt * 14;
      short8 af = {}, bf = {};
      if (quad < 2) {
        af = *(const short8*)&poBr[(mt * 16 + r16) * 96 + koff + quad * 8];
        const u16* gp = &gsb[n * 16 + r16][quad * 8];
        ((short4v*)&bf)[0] = *(const short4v*)gp;
        ((short4v*)&bf)[1] = *(const short4v*)(gp + 4);
      }
      acc[i] = __builtin_amdgcn_mfma_f32_16x16x32_bf16(af, bf, acc[i], 0, 0, 0);
    }
  }
  #pragma unroll
  for (int i = 0; i < 7; ++i) {
    int u = wid + 4 * i;
    int mt = u / 14, n = u - mt * 14;
    #pragma unroll
    for (int reg = 0; reg < 4; ++reg) {
      int cc = mt * 16 + quad * 4 + reg;
      int tok = n * 16 + r16;
      int o = cc * 256 + tok;
      src[o] = f2b(b2f(src[o]) + acc[i][reg]);
    }
  }
}

// ---------------- K9a: adaptive max pool per (t, c64) ----------------
__global__ __launch_bounds__(256) void k9_pool(const u16* __restrict__ x3, float* __restrict__ gmax)
{
  __shared__ float red[4];
  const int bid = blockIdx.x;      // t*64 + c64
  const int c64 = bid & 63;
  const int t = bid >> 6;
  const int c = c64 & 31, which = c64 >> 5;
  const int b = t / 49; const int uv = t % 49; const int u = uv / 7; const int vq = uv % 7;
  const int tid = threadIdx.x;
  float mx = -1e30f;
  if (which == 0) {
    int h = tid & 31, w0 = tid >> 5;
    #pragma unroll
    for (int r = 0; r < 4; ++r) {
      int w = w0 + 8 * r;
      mx = fmaxf(mx, b2f(x3[((b * 224 + vq * 32 + w) * 32 + c) * 256 + u * 32 + h]));
    }
  } else {
    int w = tid & 31, h0 = tid >> 5;
    #pragma unroll
    for (int r = 0; r < 4; ++r) {
      int h = h0 + 8 * r;
      mx = fmaxf(mx, b2f(x3[((896 + b * 224 + u * 32 + h) * 32 + c) * 256 + vq * 32 + w]));
    }
  }
  #pragma unroll
  for (int m = 32; m >= 1; m >>= 1) mx = fmaxf(mx, __shfl_xor(mx, m));
  if ((tid & 63) == 0) red[tid >> 6] = mx;
  __syncthreads();
  if (tid == 0)
    gmax[t * 64 + c64] = fmaxf(fmaxf(red[0], red[1]), fmaxf(red[2], red[3]));
}

// ---------------- K9c: FC gate (inlined, bit-identical order) + gated combine ----------------
__global__ __launch_bounds__(256) void k9_final(const u16* __restrict__ x3,
    const float* __restrict__ gmax, const float* __restrict__ f1,
    const float* __restrict__ f2, float* __restrict__ out)
{
  __shared__ float o1s[32][33];
  __shared__ float g1s[8];
  __shared__ float gs;
  const int bid = blockIdx.x;   // t*32 + c
  const int c = bid & 31;
  const int t = bid >> 5;
  const int b = t / 49; const int uv = t % 49; const int u = uv / 7; const int vq = uv % 7;
  const int tid = threadIdx.x;
  #pragma unroll
  for (int r = 0; r < 4; ++r) {
    int h = tid & 31; int w = (tid >> 5) + 8 * r;
    o1s[w][h] = b2f(x3[((b * 224 + vq * 32 + w) * 32 + c) * 256 + u * 32 + h]);
  }
  if (tid < 8) {   // replicate k9_fc's g1[o] with identical c2 order
    float a = 0.f;
    for (int c2 = 0; c2 < 64; ++c2) a += f1[tid * 64 + c2] * gmax[t * 64 + c2];
    g1s[tid] = (a >= 0.f) ? a : 0.1f * a;
  }
  __syncthreads();
  if (tid == 0) {  // replicate k9_fc's gate with identical o order
    float a = 0.f;
    #pragma unroll
    for (int o = 0; o < 8; ++o) a += f2[c * 8 + o] * g1s[o];
    gs = 1.f / (1.f + expf(-a));
  }
  __syncthreads();
  const float g = gs;
  #pragma unroll
  for (int r = 0; r < 4; ++r) {
    int w = tid & 31; int h = (tid >> 5) + 8 * r;
    float o2 = b2f(x3[((896 + b * 224 + u * 32 + h) * 32 + c) * 256 + vq * 32 + w]);
    float o1 = o1s[w][h];
    out[(t * 32 + c) * 1024 + h * 32 + w] = o1 * g + o2 * (1.f - g);
  }
}

extern "C" void kernel_launch(void* const* d_in, const int* in_sizes, int n_in,
                              void* d_out, int out_size, void* d_ws, size_t ws_size,
                              hipStream_t stream)
{
  const float* xlf    = (const float*)d_in[0];
  const float* h_lin  = (const float*)d_in[1];
  const float* h_temp = (const float*)d_in[2];
  const float* h_g1   = (const float*)d_in[3];
  const float* h_b1   = (const float*)d_in[4];
  const float* h_qkv  = (const float*)d_in[5];
  const float* h_qdw  = (const float*)d_in[6];
  const float* h_proj = (const float*)d_in[7];
  const float* h_ca   = (const float*)d_in[8];
  const float* h_ge   = (const float*)d_in[9];
  const float* h_be   = (const float*)d_in[10];
  const float* h_pin  = (const float*)d_in[11];
  const float* h_dw   = (const float*)d_in[12];
  const float* h_po   = (const float*)d_in[13];
  const float* v_lin  = (const float*)d_in[14];
  const float* v_temp = (const float*)d_in[15];
  const float* v_g1   = (const float*)d_in[16];
  const float* v_b1   = (const float*)d_in[17];
  const float* v_qkv  = (const float*)d_in[18];
  const float* v_qdw  = (const float*)d_in[19];
  const float* v_proj = (const float*)d_in[20];
  const float* v_ca   = (const float*)d_in[21];
  const float* v_ge   = (const float*)d_in[22];
  const float* v_be   = (const float*)d_in[23];
  const float* v_pin  = (const float*)d_in[24];
  const float* v_dw   = (const float*)d_in[25];
  const float* v_po   = (const float*)d_in[26];
  const float* f1     = (const float*)d_in[27];
  const float* f2     = (const float*)d_in[28];

  char* w = (char*)d_ws;
  u16*   x2    = (u16*)  (w + 0);          // 29,360,128 B (rows padded to 256)
  float* xqp   = (float*)(w + 0);          // 29,360,128 B: 32 partials (aliases x2; dead by k7)
  float* qkvp  = (float*)(w + 29360128);   //  2,752,512 B
  float* qkvn  = (float*)(w + 32112640);   //  2,752,512 B
  float* gmax  = (float*)(w + 34865152);   //     50,176 B
  u16*   pinB  = (u16*)  (w + 34940416);   //     24,576 B
  u16*   poB   = (u16*)  (w + 34964992);   //     12,288 B
  u16*   qkvwB = (u16*)  (w + 34977280);   //    196,608 B
  u16*   aoB   = (u16*)  (w + 35173888);   //    458,752 B (k6 -> k7)
  u16*   linwB = (u16*)  (w + 35632640);   //  3,670,016 B
  u16*   projB = (u16*)  (w + 39302656);   //  3,670,016 B
  u16*   xn    = (u16*)  (w + 42972672);   //    458,752 B (k1b -> k3)
  // total ws used: 43,431,424 B (~41.4 MB; ws >= 52.6 MB proven R3)

  k_prep   <<<4040, 256, 0, stream>>>(h_lin, v_lin, h_proj, v_proj,
                                      h_pin, v_pin, h_po, v_po, h_qkv, v_qkv,
                                      linwB, projB, pinB, poB, qkvwB);
  k1_mfma  <<<dim3(32, 4, 8), 256, 0, stream>>>(xlf, linwB, xqp);
  k1b_ln   <<<112, 256, 0, stream>>>(xqp, h_g1, h_b1, v_g1, v_b1, xn);
  k3_mfma  <<<dim3(6, 2, 8), 256, 0, stream>>>(xn, qkvwB, qkvp);
  k45_dwheads <<<192, 256, 0, stream>>>(qkvp, h_qdw, v_qdw, qkvn);
  k6_attn  <<<dim3(56, 4, 2), 256, 0, stream>>>(qkvn, h_temp, v_temp, h_ca, v_ca, aoB);
  k7_mfma  <<<dim3(28, 4, 8), 256, 0, stream>>>(aoB, projB, xlf, x2);
  k8_mfma  <<<dim3(896, 2), 256, 0, stream>>>(x2, h_ge, h_be, v_ge, v_be,
                                              h_dw, v_dw, pinB, poB);
  k9_pool  <<<12544, 256, 0, stream>>>(x2, gmax);
  k9_final <<<6272, 256, 0, stream>>>(x2, gmax, f1, f2, (float*)d_out);
}

// Round 12
// 383.345 us; speedup vs baseline: 1.0765x; 1.0765x over previous
//
#include <hip/hip_runtime.h>
#include <math.h>

typedef unsigned short u16;
typedef unsigned int   u32;
typedef __attribute__((ext_vector_type(8))) short short8;
typedef __attribute__((ext_vector_type(4))) short short4v;
typedef __attribute__((ext_vector_type(4))) float float4v;
typedef __attribute__((ext_vector_type(2))) float float2v;
typedef __attribute__((ext_vector_type(2))) unsigned int u32x2;

#define DI __device__ __forceinline__

DI float b2f(u16 v){ return __uint_as_float(((u32)v) << 16); }
DI u16 f2b(float f){
  u32 u = __float_as_uint(f);
  u32 r = (u + 0x7fffu + ((u >> 16) & 1u)) >> 16;
  return (u16)r;
}
// order-preserving u32 encoding of float (for atomicMax-based fmax)
DI u32 ford(u32 u){ return ((int)u < 0) ? ~u : (u | 0x80000000u); }
DI float fdec(u32 m){ u32 u = (m & 0x80000000u) ? (m ^ 0x80000000u) : ~m; return __uint_as_float(u); }
// Branchless gelu via A&S 7.1.26 erf (|eps| <= 1.5e-7, far below bf16 noise).
DI float fast_gelu(float x){
  float ax = fabsf(x) * 0.70710678118654752f;
  float t  = __builtin_amdgcn_rcpf(fmaf(0.3275911f, ax, 1.0f));
  float p  = t * (0.254829592f + t * (-0.284496736f + t * (1.421413741f +
             t * (-1.453152027f + t * 1.061405429f))));
  float e  = __expf(-ax * ax);
  float ea = fmaf(-p, e, 1.0f);
  float er = (x >= 0.f) ? ea : -ea;
  return 0.5f * x * (1.0f + er);
}

// packed dual-FP32 FMA (CDNA VOP3P, gfx90a+)
DI float2v pk_fma(float2v a, float2v b, float2v c){
  float2v d;
  asm("v_pk_fma_f32 %0, %1, %2, %3" : "=v"(d) : "v"(a), "v"(b), "v"(c));
  return d;
}
// pack two f32 -> (bf16 lo | bf16 hi), RNE (same rounding as f2b)
DI u32 cvt_pk_bf16(float lo, float hi){
  u32 r;
  asm("v_cvt_pk_bf16_f32 %0, %1, %2" : "=v"(r) : "v"(lo), "v"(hi));
  return r;
}

// Shapes: Bb=4, A=7, C=32, H=W=32, E=128, HEADS=4, d=32, L=N=224, K_tok=7168, HID=85
// x_lf flat: [196][32][32][32] f32, img=(b*49+u*7+v), elem = img*32768 + c*1024 + h*32 + w
// branch 0 (h): token l=(u,h), reduce k=(c, n=(v,w))
// branch 1 (v): token l=(v,w), reduce k=(c, n=(u,h))
//
// Verified MFMA recipe: mfma_f32_16x16x32_bf16, operands loaded as [row][k],
// row=lane&15, k=quad*8+j (one b128); D[m][n]: m=quad*4+reg, n=lane&15.
// R15-R22 history in git. R23: k7/k3 un-staging was ~neutral-negative (non-k8
// time identical 307us; scattered 64-line B-reads) -> R24 reverts k7/k3 to the
// R22 staged forms. k8 is bimodal 90/105us across acquisitions (environmental).
// R24 (this round): pool fused into k8 epilogue. Each k8 block computes
// per-(c, tok>>5) partials (max over tok&31, LDS aliasing dead t12), then 224
// global atomicMax on order-preserving u32. k9_pool DELETED (29.4 MB re-read +
// 12544-block launch). gmax zero-init rides k_prep (+49 blocks). k9_final
// decodes. Pooled maxima bit-identical (max is order-independent).

// ---------------- k_prep: weight conversions + gmax zero ----------------
__global__ __launch_bounds__(256) void k_prep(const float* __restrict__ lw0,
    const float* __restrict__ lw1, const float* __restrict__ pw0,
    const float* __restrict__ pw1,
    const float* __restrict__ pin0, const float* __restrict__ pin1,
    const float* __restrict__ po0,  const float* __restrict__ po1,
    const float* __restrict__ qw0,  const float* __restrict__ qw1,
    u16* __restrict__ linwB, u16* __restrict__ projB,
    u16* __restrict__ pinB, u16* __restrict__ poB, u16* __restrict__ qkvwB,
    u32* __restrict__ gmaxU)
{
  if (blockIdx.x < 3584) {
    int base = blockIdx.x * 1024 + threadIdx.x;   // 3,670,016 total
    #pragma unroll
    for (int r = 0; r < 4; ++r) {
      int i = base + 256 * r;
      if (i < 1835008) {
        const float* src = (i < 917504) ? lw0 : lw1;
        linwB[i] = f2b(src[i % 917504]);
      } else if (i < 3670016) {
        int j = i - 1835008;
        const float* src = (j < 917504) ? pw0 : pw1;
        projB[j] = f2b(src[j % 917504]);
      }
    }
  } else if (blockIdx.x < 4040) {
    int idx = (blockIdx.x - 3584) * 256 + threadIdx.x;   // 116736 total
    if (idx < 12288) {
      int cc = idx & 31;
      int r = (idx >> 5) % 96;
      int hb = (idx >> 5) / 96;       // br*2+half
      int br = hb >> 1, half = hb & 1;
      const float* p = br ? pin1 : pin0;
      pinB[idx] = (r < 85) ? f2b(p[(half * 85 + r) * 32 + cc]) : (u16)0;
    } else if (idx < 18432) {
      int j = idx - 12288;
      int r = j % 96;
      int t = j / 96;                 // br*32+cc
      int br = t >> 5, cc = t & 31;
      const float* p = br ? po1 : po0;
      poB[j] = (r < 85) ? f2b(p[cc * 85 + r]) : (u16)0;
    } else if (idx < 116736) {
      int j = idx - 18432;            // [br][384][128]
      int br = j / 49152, rest = j % 49152;
      qkvwB[j] = f2b((br ? qw1 : qw0)[rest]);
    }
  } else {
    int idx = (blockIdx.x - 4040) * 256 + threadIdx.x;   // 12544 total
    if (idx < 12544) gmaxU[idx] = 0u;
  }
}

// ---------------- K1a (MFMA): token GEMM partials -> xqp[ks][bb][tok][e] ----------------
// R21: ks 0..31 (c = ks), 7 steps of 32 k. A float4 / W short4 wide staging.
__global__ __launch_bounds__(256) void k1_mfma(const float* __restrict__ xlf,
    const u16* __restrict__ linwB, float* __restrict__ xqp)
{
  __shared__ __align__(16) u16 Asb[64][40];
  __shared__ __align__(16) u16 Wsb[128][40];
  const int ks   = blockIdx.x;   // 0..31, channel c = ks
  const int mblk = blockIdx.y;   // 0..3
  const int bb   = blockIdx.z;   // br*4+b
  const int br = bb >> 2, b = bb & 3;
  const int tid = threadIdx.x;
  const int wid = tid >> 6, lane = tid & 63;
  const int quad = lane >> 4, r16 = lane & 15;
  const int m0s = mblk * 64 + wid * 16;
  const bool active = (m0s < 224);
  const u16* wsrc = linwB + br * 917504;
  const int c = ks;

  float4v acc[8];
  #pragma unroll
  for (int nt = 0; nt < 8; ++nt) acc[nt] = (float4v){0.f, 0.f, 0.f, 0.f};

  #pragma unroll 1
  for (int step = 0; step < 7; ++step) {
    const int k0 = ks * 224 + step * 32;
    #pragma unroll
    for (int r = 0; r < 2; ++r) {
      int idx = tid + 256 * r;           // < 512
      if (br == 0) {
        int ml = idx >> 3, kl4 = idx & 7;
        int l = mblk * 64 + ml;
        float4v v4 = {0.f, 0.f, 0.f, 0.f};
        if (l < 224) {
          int u = l >> 5, h = l & 31;
          v4 = *(const float4v*)&xlf[(b * 49 + u * 7 + step) * 32768 + c * 1024 + h * 32 + kl4 * 4];
        }
        u32 lo = cvt_pk_bf16(v4[0], v4[1]);
        u32 hi = cvt_pk_bf16(v4[2], v4[3]);
        *(u32x2*)&Asb[ml][kl4 * 4] = (u32x2){lo, hi};
      } else {
        int ml4 = idx & 15, kl = idx >> 4;
        int ml0 = ml4 * 4;
        int l0 = mblk * 64 + ml0;
        float4v v4 = {0.f, 0.f, 0.f, 0.f};
        if (l0 < 224) {
          int v2 = l0 >> 5, w2 = l0 & 31;
          v4 = *(const float4v*)&xlf[(b * 49 + step * 7 + v2) * 32768 + c * 1024 + kl * 32 + w2];
        }
        Asb[ml0 + 0][kl] = f2b(v4[0]);
        Asb[ml0 + 1][kl] = f2b(v4[1]);
        Asb[ml0 + 2][kl] = f2b(v4[2]);
        Asb[ml0 + 3][kl] = f2b(v4[3]);
      }
    }
    #pragma unroll
    for (int r = 0; r < 4; ++r) {
      int idx = tid + 256 * r;           // < 1024
      int e = idx >> 3, kl4 = idx & 7;
      *(short4v*)&Wsb[e][kl4 * 4] = *(const short4v*)&wsrc[e * 7168 + k0 + kl4 * 4];
    }
    __syncthreads();
    if (active) {
      short8 af = *(const short8*)&Asb[wid * 16 + r16][quad * 8];
      #pragma unroll
      for (int nt = 0; nt < 8; ++nt) {
        short8 bf = *(const short8*)&Wsb[nt * 16 + r16][quad * 8];
        acc[nt] = __builtin_amdgcn_mfma_f32_16x16x32_bf16(af, bf, acc[nt], 0, 0, 0);
      }
    }
    __syncthreads();
  }
  if (active) {
    float* outp = xqp + ks * 229376 + (bb * 224 + m0s) * 128;
    #pragma unroll
    for (int nt = 0; nt < 8; ++nt) {
      int e = nt * 16 + r16;
      #pragma unroll
      for (int reg = 0; reg < 4; ++reg) {
        int tok = quad * 4 + reg;
        outp[tok * 128 + e] = acc[nt][reg];
      }
    }
  }
}

// ---------------- K1b: reduce 32 partials + LayerNorm(E) -> xn bf16 [bb][tok][e] ----------------
__global__ __launch_bounds__(256) void k1b_ln(const float* __restrict__ xqp,
    const float* __restrict__ g0, const float* __restrict__ b0,
    const float* __restrict__ g1, const float* __restrict__ b1,
    u16* __restrict__ xn)
{
  const int tid = threadIdx.x;
  const int row = blockIdx.x * 16 + (tid >> 4);   // (bb*224+tok), 0..1791
  const int p = tid & 15;
  const int bb = row / 224;
  const int br = bb >> 2;
  const float* lg = br ? g1 : g0;
  const float* lb = br ? b1 : b0;
  const int e0 = p * 8;
  float4v a0 = {0.f,0.f,0.f,0.f}, a1 = {0.f,0.f,0.f,0.f};
  const float* src = xqp + row * 128 + e0;
  #pragma unroll
  for (int ks = 0; ks < 32; ++ks) {
    const float4v* sp = (const float4v*)(src + ks * 229376);
    a0 += sp[0];
    a1 += sp[1];
  }
  float s = 0.f, s2 = 0.f;
  #pragma unroll
  for (int j = 0; j < 4; ++j) {
    s  += a0[j] + a1[j];
    s2 += a0[j] * a0[j] + a1[j] * a1[j];
  }
  #pragma unroll
  for (int m = 8; m >= 1; m >>= 1) {
    s  += __shfl_xor(s, m);
    s2 += __shfl_xor(s2, m);
  }
  float mean = s * (1.f / 128.f);
  float var  = s2 * (1.f / 128.f) - mean * mean;
  float rs   = rsqrtf(fmaxf(var, 0.f) + 1e-6f);
  u16 o[8];
  #pragma unroll
  for (int j = 0; j < 4; ++j) {
    o[j]     = f2b((a0[j] - mean) * rs * lg[e0 + j]     + lb[e0 + j]);
    o[4 + j] = f2b((a1[j] - mean) * rs * lg[e0 + 4 + j] + lb[e0 + 4 + j]);
  }
  *(short8*)&xn[row * 128 + e0] = *(const short8*)o;
}

// ---------------- K3 (MFMA): qkv 1x1 on pre-LN'd xn -> qkvp[bb][384][224] ----------------
// R22 form: token halves, staged xnb (31,360 B), grid (6,2,8).
__global__ __launch_bounds__(256) void k3_mfma(const u16* __restrict__ xn,
    const u16* __restrict__ qkvwB, float* __restrict__ qkvp)
{
  __shared__ u16 xnb[112][140];   // 31,360 B
  const int mchunk = blockIdx.x;  // 0..5
  const int nh = blockIdx.y;      // 0..1 token half
  const int bb = blockIdx.z;
  const int br = bb >> 2;
  const int tid = threadIdx.x;
  const int wid = tid >> 6, lane = tid & 63;
  const int quad = lane >> 4, r16 = lane & 15;

  #pragma unroll
  for (int i = 0; i < 7; ++i) {
    int idx = tid + 256 * i;      // 1792
    int row = idx >> 4, c8 = idx & 15;
    *(short8*)&xnb[row][c8 * 8] = *(const short8*)&xn[(bb * 224 + nh * 112 + row) * 128 + c8 * 8];
  }
  __syncthreads();

  const int mtile = mchunk * 64 + wid * 16;   // < 384
  const u16* wsrc = qkvwB + br * 49152;
  float4v acc[7];
  #pragma unroll
  for (int nt = 0; nt < 7; ++nt) acc[nt] = (float4v){0.f, 0.f, 0.f, 0.f};
  #pragma unroll
  for (int k = 0; k < 4; ++k) {
    short8 af = *(const short8*)&wsrc[(mtile + r16) * 128 + k * 32 + quad * 8];
    #pragma unroll
    for (int nt = 0; nt < 7; ++nt) {
      short8 bf = *(const short8*)&xnb[nt * 16 + r16][k * 32 + quad * 8];
      acc[nt] = __builtin_amdgcn_mfma_f32_16x16x32_bf16(af, bf, acc[nt], 0, 0, 0);
    }
  }
  #pragma unroll
  for (int nt = 0; nt < 7; ++nt) {
    int tok = nh * 112 + nt * 16 + r16;
    #pragma unroll
    for (int reg = 0; reg < 4; ++reg) {
      int o = mtile + quad * 4 + reg;
      qkvp[(bb * 384 + o) * 224 + tok] = acc[nt][reg];
    }
  }
}

// ---------------- K45: dw3x3 + head split + l2norm(q,k) -> qkvn[bb][sel][h][l][d] ----------------
__global__ __launch_bounds__(256) void k45_dwheads(const float* __restrict__ qkvp,
    const float* __restrict__ dw0, const float* __restrict__ dw1,
    float* __restrict__ qkvn)
{
  __shared__ float ps[32][161];
  __shared__ float ts[32][137];
  __shared__ float scs[128];
  const int bid = blockIdx.x;          // 192 blocks
  const int half = bid & 1;
  const int rest = bid >> 1;           // bb*12 + sel*4 + h
  const int h = rest & 3;
  const int sel = (rest >> 2) % 3;
  const int bb = rest / 12;
  const int br = bb >> 2;
  const int tid = threadIdx.x;
  const int o0 = sel * 128 + h * 32;
  const float* src = qkvp + (bb * 384 + o0) * 224;
  const float* dwa = (br ? dw1 : dw0) + o0 * 9;
  const int vin0  = half ? 3 : 0;
  const int nin   = half ? 128 : 160;
  const int vout0 = half ? 4 : 0;
  const int nout  = half ? 96 : 128;
  const int lout0 = vout0 * 32;
  for (int idx = tid; idx < 32 * nin; idx += 256) {
    int d = idx / nin, l = idx - d * nin;
    ps[d][l] = src[d * 224 + vin0 * 32 + l];
  }
  __syncthreads();
  for (int idx = tid; idx < 32 * nout; idx += 256) {
    int d = idx / nout, lo = idx - d * nout;
    int l = lout0 + lo;
    int v = l >> 5, w = l & 31;
    const float* dww = dwa + d * 9;
    float acc = 0.f;
    #pragma unroll
    for (int dy = -1; dy <= 1; ++dy) {
      int vv = v + dy; if (vv < 0 || vv > 6) continue;
      int vloc = vv - vin0;
      #pragma unroll
      for (int dx = -1; dx <= 1; ++dx) {
        int ww = w + dx; if (ww < 0 || ww > 31) continue;
        acc += ps[d][vloc * 32 + ww] * dww[(dy + 1) * 3 + (dx + 1)];
      }
    }
    ts[d][lo] = acc;
  }
  __syncthreads();
  if (tid < nout) {
    float ss = 0.f;
    #pragma unroll 8
    for (int d = 0; d < 32; ++d) { float x = ts[d][tid]; ss += x * x; }
    scs[tid] = (sel < 2) ? (1.0f / fmaxf(sqrtf(ss), 1e-12f)) : 1.0f;
  }
  __syncthreads();
  float* dst = qkvn + ((bb * 3 + sel) * 4 + h) * 7168;
  for (int idx = tid; idx < 32 * nout; idx += 256) {
    int d = idx & 31, lo = idx >> 5;
    dst[(lout0 + lo) * 32 + d] = ts[d][lo] * scs[lo];
  }
}

// ---------------- K6: fused attention -> aoB[bb][tok][e] bf16 ----------------
__global__ __launch_bounds__(256) void k6_attn(const float* __restrict__ qkvn,
    const float* __restrict__ tmp0, const float* __restrict__ tmp1,
    const float* __restrict__ ca0,  const float* __restrict__ ca1,
    u16* __restrict__ aoB)
{
  __shared__ float qs[16][33];
  __shared__ float ks[128][33];
  __shared__ float sS[16 * 228];
  __shared__ float mxs[16], rss[16];
  __shared__ float caf[32], tpf[4];
  const int it = blockIdx.x;        // 0..55 i-tile (4 rows)
  const int b = blockIdx.y, br = blockIdx.z;
  const int bb = br * 4 + b;
  const int tid = threadIdx.x;
  const float* tw = br ? tmp1 : tmp0;
  const float* cw = br ? ca1 : ca0;
  if (tid < 32) caf[tid] = cw[tid];
  if (tid < 4)  tpf[tid] = tw[tid];
  const int i0 = it * 4;
  const float* qb = qkvn + (bb * 3 + 0) * 4 * 7168;
  const float* kb = qkvn + (bb * 3 + 1) * 4 * 7168;
  const float* vb = qkvn + (bb * 3 + 2) * 4 * 7168;
  #pragma unroll
  for (int r = 0; r < 2; ++r) {
    int idx = tid + 256 * r;
    if (idx < 512) {
      int d = idx & 31, i = (idx >> 5) & 3, h = idx >> 7;
      qs[h * 4 + i][d] = qb[h * 7168 + (i0 + i) * 32 + d];
    }
  }
  __syncthreads();
  const int hC = tid >> 6, iC = (tid >> 4) & 3, jq = tid & 15;
  float qv[32];
  #pragma unroll
  for (int d2 = 0; d2 < 32; ++d2) qv[d2] = qs[hC * 4 + iC][d2];
  for (int jt = 0; jt < 7; ++jt) {
    __syncthreads();
    #pragma unroll
    for (int r = 0; r < 16; ++r) {
      int idx = tid + 256 * r;
      int d = idx & 31, jj = (idx >> 5) & 31, h = idx >> 10;
      ks[h * 32 + jj][d] = kb[h * 7168 + (jt * 32 + jj) * 32 + d];
    }
    __syncthreads();
    float a2[2] = {0.f, 0.f};
    for (int d = 0; d < 32; ++d) {
      #pragma unroll
      for (int r = 0; r < 2; ++r) a2[r] += qv[d] * ks[hC * 32 + jq + 16 * r][d];
    }
    #pragma unroll
    for (int r = 0; r < 2; ++r)
      sS[(hC * 4 + iC) * 228 + jt * 32 + jq + 16 * r] = a2[r] * tpf[hC];
  }
  __syncthreads();
  { // softmax stats per row (16 rows, 16 lanes each)
    int p = tid & 15, row = tid >> 4;
    float mx = -1e30f;
    for (int q = 0; q < 14; ++q) mx = fmaxf(mx, sS[row * 228 + p + 16 * q]);
    #pragma unroll
    for (int m = 8; m >= 1; m >>= 1) mx = fmaxf(mx, __shfl_xor(mx, m));
    float es = 0.f;
    for (int q = 0; q < 14; ++q) es += __expf(sS[row * 228 + p + 16 * q] - mx);
    #pragma unroll
    for (int m = 8; m >= 1; m >>= 1) es += __shfl_xor(es, m);
    if (p == 0) { mxs[row] = mx; rss[row] = 1.0f / es; }
  }
  __syncthreads();
  for (int q = 0; q < 4; ++q) {
    int pr = tid + 256 * q;
    if (pr < 896) {
      int i = pr / 224, j = pr % 224;
      float a1[4];
      #pragma unroll
      for (int hh = 0; hh < 4; ++hh) {
        float sv = sS[(hh * 4 + i) * 228 + j];
        float z = fmaxf(sv, 0.f); float z2 = z * z;
        a1[hh] = fast_gelu(z2) * z2;
      }
      #pragma unroll
      for (int hh = 0; hh < 4; ++hh) {
        float sc = 0.f, sh = 0.f;
        #pragma unroll
        for (int k2 = 0; k2 < 4; ++k2) { sc += caf[hh * 4 + k2] * a1[k2]; sh += caf[(hh + 4) * 4 + k2] * a1[k2]; }
        int row = hh * 4 + i;
        float at = __expf(sS[row * 228 + j] - mxs[row]) * rss[row];
        sS[row * 228 + j] = at * (1.f + sc) + sh;
      }
    }
  }
  __syncthreads();
  { // PV with per-32-token V tiles staged in LDS (ks[] reused) -> aoB bf16
    int d = tid & 31, hpair = (tid >> 5) & 1, rg = tid >> 6;   // rg in [0,4)
    float acc[2] = {0.f, 0.f};
    for (int jt = 0; jt < 7; ++jt) {
      __syncthreads();
      #pragma unroll
      for (int r = 0; r < 16; ++r) {
        int idx = tid + 256 * r;
        int dd = idx & 31, jj = (idx >> 5) & 31, hh2 = idx >> 10;
        ks[hh2 * 32 + jj][dd] = vb[hh2 * 7168 + (jt * 32 + jj) * 32 + dd];
      }
      __syncthreads();
      for (int j = 0; j < 32; ++j) {
        #pragma unroll
        for (int c2 = 0; c2 < 2; ++c2) {
          int hh = hpair * 2 + c2;
          acc[c2] += sS[(hh * 4 + rg) * 228 + jt * 32 + j] * ks[hh * 32 + j][d];
        }
      }
    }
    #pragma unroll
    for (int c2 = 0; c2 < 2; ++c2) {
      int hh = hpair * 2 + c2;
      aoB[(bb * 224 + i0 + rg) * 128 + hh * 32 + d] = f2b(acc[c2]);
    }
  }
}

// ---------------- K7 (MFMA): proj GEMM + residual -> x2 (bf16, X2S=256 rows) ----------------
// R22 form: Bs staged (62,720 B) + Ts transpose epilogue; grid (28,4,8).
__global__ __launch_bounds__(256) void k7_mfma(const u16* __restrict__ aoB,
    const u16* __restrict__ projB, const float* __restrict__ xlf, u16* __restrict__ x2)
{
  __shared__ u16 Bs[224][140];    // 62,720 B
  __shared__ float Ts[64][68];    // 17,408 B
  const int mchunk = blockIdx.x;  // 0..27
  const int mi = blockIdx.y;      // 0..3
  const int bb = blockIdx.z;
  const int br = bb >> 2, b = bb & 3;
  const int tid = threadIdx.x;
  const int wid = tid >> 6, lane = tid & 63;
  const int quad = lane >> 4, r16 = lane & 15;
  const u16* asrc = projB + br * 917504;
  #pragma unroll
  for (int i = 0; i < 14; ++i) {
    int idx = tid + 256 * i;      // 3584
    int row = idx >> 4, c8 = idx & 15;
    *(short8*)&Bs[row][c8 * 8] = *(const short8*)&aoB[(bb * 224 + row) * 128 + c8 * 8];
  }
  __syncthreads();
  const int mbase = mchunk * 256 + (wid * 4 + mi) * 16;
  float4v acc[14];
  #pragma unroll
  for (int nt = 0; nt < 14; ++nt) acc[nt] = (float4v){0.f, 0.f, 0.f, 0.f};
  #pragma unroll
  for (int k = 0; k < 4; ++k) {
    short8 af = *(const short8*)&asrc[(mbase + r16) * 128 + k * 32 + quad * 8];
    #pragma unroll
    for (int nt = 0; nt < 14; ++nt) {
      short8 bf = *(const short8*)&Bs[nt * 16 + r16][k * 32 + quad * 8];
      acc[nt] = __builtin_amdgcn_mfma_f32_16x16x32_bf16(af, bf, acc[nt], 0, 0, 0);
    }
  }
  #pragma unroll
  for (int rd = 0; rd < 4; ++rd) {
    const int ntn = (rd < 3) ? 4 : 2;
    __syncthreads();
    #pragma unroll
    for (int t = 0; t < 4; ++t) {
      if (t < ntn) {
        #pragma unroll
        for (int reg = 0; reg < 4; ++reg)
          Ts[wid * 16 + quad * 4 + reg][t * 16 + r16] = acc[rd * 4 + t][reg];
      }
    }
    __syncthreads();
    const int nq = ntn * 4;
    #pragma unroll
    for (int pass = 0; pass < 4; ++pass) {
      int idx = tid + 256 * pass;
      if (idx < 64 * nq) {
        int rloc = idx / nq;
        int qc = idx - rloc * nq;
        int row = mchunk * 256 + (((rloc >> 4) * 4 + mi) << 4) + (rloc & 15);
        int c = row / 224, n = row - c * 224;
        int l = rd * 64 + qc * 4;
        float4v tv = *(const float4v*)&Ts[rloc][qc * 4];
        float r0v, r1v, r2v, r3v;
        if (br == 0) {
          int img = b * 49 + (l >> 5) * 7 + (n >> 5);
          const float* xp = xlf + img * 32768 + c * 1024 + (l & 31) * 32 + (n & 31);
          r0v = xp[0]; r1v = xp[32]; r2v = xp[64]; r3v = xp[96];
        } else {
          int img = b * 49 + (n >> 5) * 7 + (l >> 5);
          float4v xv = *(const float4v*)(xlf + img * 32768 + c * 1024 + (n & 31) * 32 + (l & 31));
          r0v = xv[0]; r1v = xv[1]; r2v = xv[2]; r3v = xv[3];
        }
        u32 lo = cvt_pk_bf16(tv[0] + r0v, tv[1] + r1v);
        u32 hi = cvt_pk_bf16(tv[2] + r2v, tv[3] + r3v);
        u16* dp = &x2[(((br * 896 + b * 224 + n) * 32 + c) << 8) + l];
        *(u32x2*)dp = (u32x2){lo, hi};
      }
    }
  }
}

// ---------------- K8 (MFMA): LN(C)+pin+dw3x3+gelu gate+pout+residual+POOL ----------------
// R14 structure (6 chunks, pipelined pout). R24: epilogue also computes pooled
// max partials per (c, tok>>5) into LDS (aliases dead t12), then 224 global
// atomicMax (order-preserving u32). LDS unchanged -> 4 blocks/CU.
__global__ __launch_bounds__(256, 4) void k8_mfma(u16* x2,
    const float* __restrict__ lg0, const float* __restrict__ lb0,
    const float* __restrict__ lg1, const float* __restrict__ lb1,
    const float* __restrict__ dwa0, const float* __restrict__ dwa1,
    const u16* __restrict__ pinB, const u16* __restrict__ poB,
    u32* __restrict__ gmaxU)
{
  __shared__ __align__(16) u16 xnb[224][36];   // 16,128 B
  __shared__ __align__(16) u32 t12[16][231];   // 14,784 B  (t1 lo | tg hi), col = v*33+w
  __shared__ __align__(16) u16 gsb[224][20];   // 8,960 B
  const int img = blockIdx.x;    // 0..895
  const int br  = blockIdx.y;
  const float* lg  = br ? lg1 : lg0;
  const float* lb  = br ? lb1 : lb0;
  const float* dww = br ? dwa1 : dwa0;
  const u16* pinBr = pinB + br * 2 * 96 * 32;
  const u16* poBr  = poB + br * 32 * 96;
  const int tid = threadIdx.x;
  const int wid = tid >> 6, lane = tid & 63;
  const int quad = lane >> 4, r16 = lane & 15;
  u16* src = x2 + (br * 896 + img) * 8192;

  if (tid < 224) {
    float xr[32];
    #pragma unroll
    for (int cc = 0; cc < 32; ++cc) xr[cc] = b2f(src[cc * 256 + tid]);
    float s = 0.f, s2 = 0.f;
    #pragma unroll
    for (int cc = 0; cc < 32; ++cc) { s += xr[cc]; s2 += xr[cc] * xr[cc]; }
    float mean = s * (1.f / 32.f);
    float var  = s2 * (1.f / 32.f) - mean * mean;
    float rs   = rsqrtf(fmaxf(var, 0.f) + 1e-6f);
    #pragma unroll
    for (int cc = 0; cc < 32; ++cc)
      xnb[tid][cc] = f2b((xr[cc] - mean) * rs * lg[cc] + lb[cc]);
  }
  __syncthreads();

  float4v acc[7];
  #pragma unroll
  for (int i = 0; i < 7; ++i) acc[i] = (float4v){0.f, 0.f, 0.f, 0.f};

  #pragma unroll 1
  for (int it = 0; it < 6; ++it) {
    const int r0 = it * 16;
    #pragma unroll
    for (int ni = 0; ni < 4; ++ni) {
      int n = wid + 4 * ni;
      if (n < 14) {
        const int tok = n * 16 + r16;
        short8 bf;
        const u16* xp = &xnb[tok][quad * 8];
        ((short4v*)&bf)[0] = *(const short4v*)xp;
        ((short4v*)&bf)[1] = *(const short4v*)(xp + 4);
        short8 af0 = *(const short8*)&pinBr[((r0 + r16) << 5) + quad * 8];
        short8 af1 = *(const short8*)&pinBr[((96 + r0 + r16) << 5) + quad * 8];
        float4v d0 = __builtin_amdgcn_mfma_f32_16x16x32_bf16(af0, bf,
                       (float4v){0.f, 0.f, 0.f, 0.f}, 0, 0, 0);
        float4v d1 = __builtin_amdgcn_mfma_f32_16x16x32_bf16(af1, bf,
                       (float4v){0.f, 0.f, 0.f, 0.f}, 0, 0, 0);
        const int col = tok + (tok >> 5);     // v*33 + w
        #pragma unroll
        for (int reg = 0; reg < 4; ++reg)
          t12[quad * 4 + reg][col] = cvt_pk_bf16(d0[reg], d1[reg]);
      }
    }
    if (it > 0) {
      const int koff = (it - 1) * 16;
      #pragma unroll
      for (int i = 0; i < 7; ++i) {
        int u = wid + 4 * i;
        int mt = u / 14, n = u - mt * 14;
        short8 af = {}, bf = {};
        if (quad < 2) {
          af = *(const short8*)&poBr[(mt * 16 + r16) * 96 + koff + quad * 8];
          const u16* gp = &gsb[n * 16 + r16][quad * 8];
          ((short4v*)&bf)[0] = *(const short4v*)gp;
          ((short4v*)&bf)[1] = *(const short4v*)(gp + 4);
        }
        acc[i] = __builtin_amdgcn_mfma_f32_16x16x32_bf16(af, bf, acc[i], 0, 0, 0);
      }
    }
    __syncthreads();
    if (tid < 224) {
      const int rl = tid & 15;
      const int v  = tid >> 5;
      const int wh = (tid >> 4) & 1;
      const int r  = r0 + rl;
      float2v wp[9];
      if (r < 85) {
        const float* w1 = dww + r * 9;
        const float* w2 = dww + (85 + r) * 9;
        #pragma unroll
        for (int t = 0; t < 9; ++t) wp[t] = (float2v){w1[t], w2[t]};
      } else {
        #pragma unroll
        for (int t = 0; t < 9; ++t) wp[t] = (float2v){0.f, 0.f};
      }
      const u32* trow = &t12[rl][0];
      const int c0 = v * 33;
      const int base = wh << 4;
      const bool vok0 = (v > 0), vok2 = (v < 6);
      float2v accP = {0.f, 0.f}, accC = {0.f, 0.f}, accN = {0.f, 0.f};
      #pragma unroll
      for (int it2 = 0; it2 < 18; ++it2) {
        bool cok = true;
        if (it2 == 0)  cok = (wh == 1);
        if (it2 == 17) cok = (wh == 0);
        if (cok) {
          const int cw = base - 1 + it2;
          u32 p0 = vok0 ? trow[c0 - 33 + cw] : 0u;
          u32 p1 =        trow[c0 + cw];
          u32 p2 = vok2 ? trow[c0 + 33 + cw] : 0u;
          float2v x0 = {__uint_as_float(p0 << 16), __uint_as_float(p0 & 0xffff0000u)};
          float2v x1 = {__uint_as_float(p1 << 16), __uint_as_float(p1 & 0xffff0000u)};
          float2v x2v = {__uint_as_float(p2 << 16), __uint_as_float(p2 & 0xffff0000u)};
          accP = pk_fma(x0, wp[2], accP);
          accC = pk_fma(x0, wp[1], accC);
          accN = pk_fma(x0, wp[0], accN);
          accP = pk_fma(x1, wp[5], accP);
          accC = pk_fma(x1, wp[4], accC);
          accN = pk_fma(x1, wp[3], accN);
          accP = pk_fma(x2v, wp[8], accP);
          accC = pk_fma(x2v, wp[7], accC);
          accN = pk_fma(x2v, wp[6], accN);
        }
        if (it2 >= 2) {
          float g = fast_gelu(accP[0]) * accP[1];
          gsb[(v << 5) + base + (it2 - 2)][rl] = f2b(g);
        }
        accP = accC; accC = accN; accN = (float2v){0.f, 0.f};
      }
    }
    __syncthreads();
  }
  { // trailing pout for chunk 5
    const int koff = 80;
    #pragma unroll
    for (int i = 0; i < 7; ++i) {
      int u = wid + 4 * i;
      int mt = u / 14, n = u - mt * 14;
      short8 af = {}, bf = {};
      if (quad < 2) {
        af = *(const short8*)&poBr[(mt * 16 + r16) * 96 + koff + quad * 8];
        const u16* gp = &gsb[n * 16 + r16][quad * 8];
        ((short4v*)&bf)[0] = *(const short4v*)gp;
        ((short4v*)&bf)[1] = *(const short4v*)(gp + 4);
      }
      acc[i] = __builtin_amdgcn_mfma_f32_16x16x32_bf16(af, bf, acc[i], 0, 0, 0);
    }
  }
  // ---- epilogue: residual RMW + pooled-max partials (pm aliases dead t12) ----
  u32* pm = (u32*)t12;     // 224 cells: pm[c*7 + (tok>>5)]
  for (int idx2 = tid; idx2 < 224; idx2 += 256) pm[idx2] = 0u;
  __syncthreads();
  #pragma unroll
  for (int i = 0; i < 7; ++i) {
    int u = wid + 4 * i;
    int mt = u / 14, n = u - mt * 14;
    #pragma unroll
    for (int reg = 0; reg < 4; ++reg) {
      int cc = mt * 16 + quad * 4 + reg;
      int tok = n * 16 + r16;
      int o = cc * 256 + tok;
      u16 h16 = f2b(b2f(src[o]) + acc[i][reg]);
      src[o] = h16;
      atomicMax(&pm[cc * 7 + (tok >> 5)], ford(((u32)h16) << 16));
    }
  }
  __syncthreads();
  if (tid < 224) {
    int c = tid / 7, g = tid - c * 7;
    int bq = img / 224, rem = img - bq * 224;
    int t = br ? (bq * 49 + (rem >> 5) * 7 + g) : (bq * 49 + g * 7 + (rem >> 5));
    int gidx = t * 64 + (br ? 32 + c : c);
    atomicMax(&gmaxU[gidx], pm[tid]);
  }
}

// ---------------- K9c: FC gate (inlined) + gated combine ----------------
__global__ __launch_bounds__(256) void k9_final(const u16* __restrict__ x3,
    const u32* __restrict__ gmaxU, const float* __restrict__ f1,
    const float* __restrict__ f2, float* __restrict__ out)
{
  __shared__ float o1s[32][33];
  __shared__ float g1s[8];
  __shared__ float gs;
  const int bid = blockIdx.x;   // t*32 + c
  const int c = bid & 31;
  const int t = bid >> 5;
  const int b = t / 49; const int uv = t % 49; const int u = uv / 7; const int vq = uv % 7;
  const int tid = threadIdx.x;
  #pragma unroll
  for (int r = 0; r < 4; ++r) {
    int h = tid & 31; int w = (tid >> 5) + 8 * r;
    o1s[w][h] = b2f(x3[((b * 224 + vq * 32 + w) * 32 + c) * 256 + u * 32 + h]);
  }
  if (tid < 8) {   // replicate k9_fc's g1[o] with identical c2 order
    float a = 0.f;
    for (int c2 = 0; c2 < 64; ++c2) a += f1[tid * 64 + c2] * fdec(gmaxU[t * 64 + c2]);
    g1s[tid] = (a >= 0.f) ? a : 0.1f * a;
  }
  __syncthreads();
  if (tid == 0) {  // replicate k9_fc's gate with identical o order
    float a = 0.f;
    #pragma unroll
    for (int o = 0; o < 8; ++o) a += f2[c * 8 + o] * g1s[o];
    gs = 1.f / (1.f + expf(-a));
  }
  __syncthreads();
  const float g = gs;
  #pragma unroll
  for (int r = 0; r < 4; ++r) {
    int w = tid & 31; int h = (tid >> 5) + 8 * r;
    float o2 = b2f(x3[((896 + b * 224 + u * 32 + h) * 32 + c) * 256 + vq * 32 + w]);
    float o1 = o1s[w][h];
    out[(t * 32 + c) * 1024 + h * 32 + w] = o1 * g + o2 * (1.f - g);
  }
}

extern "C" void kernel_launch(void* const* d_in, const int* in_sizes, int n_in,
                              void* d_out, int out_size, void* d_ws, size_t ws_size,
                              hipStream_t stream)
{
  const float* xlf    = (const float*)d_in[0];
  const float* h_lin  = (const float*)d_in[1];
  const float* h_temp = (const float*)d_in[2];
  const float* h_g1   = (const float*)d_in[3];
  const float* h_b1   = (const float*)d_in[4];
  const float* h_qkv  = (const float*)d_in[5];
  const float* h_qdw  = (const float*)d_in[6];
  const float* h_proj = (const float*)d_in[7];
  const float* h_ca   = (const float*)d_in[8];
  const float* h_ge   = (const float*)d_in[9];
  const float* h_be   = (const float*)d_in[10];
  const float* h_pin  = (const float*)d_in[11];
  const float* h_dw   = (const float*)d_in[12];
  const float* h_po   = (const float*)d_in[13];
  const float* v_lin  = (const float*)d_in[14];
  const float* v_temp = (const float*)d_in[15];
  const float* v_g1   = (const float*)d_in[16];
  const float* v_b1   = (const float*)d_in[17];
  const float* v_qkv  = (const float*)d_in[18];
  const float* v_qdw  = (const float*)d_in[19];
  const float* v_proj = (const float*)d_in[20];
  const float* v_ca   = (const float*)d_in[21];
  const float* v_ge   = (const float*)d_in[22];
  const float* v_be   = (const float*)d_in[23];
  const float* v_pin  = (const float*)d_in[24];
  const float* v_dw   = (const float*)d_in[25];
  const float* v_po   = (const float*)d_in[26];
  const float* f1     = (const float*)d_in[27];
  const float* f2     = (const float*)d_in[28];

  char* w = (char*)d_ws;
  u16*   x2    = (u16*)  (w + 0);          // 29,360,128 B (rows padded to 256)
  float* xqp   = (float*)(w + 0);          // 29,360,128 B: 32 partials (aliases x2; dead by k7)
  float* qkvp  = (float*)(w + 29360128);   //  2,752,512 B
  float* qkvn  = (float*)(w + 32112640);   //  2,752,512 B
  u32*   gmaxU = (u32*)  (w + 34865152);   //     50,176 B (ordered-u32 encoding)
  u16*   pinB  = (u16*)  (w + 34940416);   //     24,576 B
  u16*   poB   = (u16*)  (w + 34964992);   //     12,288 B
  u16*   qkvwB = (u16*)  (w + 34977280);   //    196,608 B
  u16*   aoB   = (u16*)  (w + 35173888);   //    458,752 B (k6 -> k7)
  u16*   linwB = (u16*)  (w + 35632640);   //  3,670,016 B
  u16*   projB = (u16*)  (w + 39302656);   //  3,670,016 B
  u16*   xn    = (u16*)  (w + 42972672);   //    458,752 B (k1b -> k3)
  // total ws used: 43,431,424 B (~41.4 MB; ws >= 52.6 MB proven R3)

  k_prep   <<<4089, 256, 0, stream>>>(h_lin, v_lin, h_proj, v_proj,
                                      h_pin, v_pin, h_po, v_po, h_qkv, v_qkv,
                                      linwB, projB, pinB, poB, qkvwB, gmaxU);
  k1_mfma  <<<dim3(32, 4, 8), 256, 0, stream>>>(xlf, linwB, xqp);
  k1b_ln   <<<112, 256, 0, stream>>>(xqp, h_g1, h_b1, v_g1, v_b1, xn);
  k3_mfma  <<<dim3(6, 2, 8), 256, 0, stream>>>(xn, qkvwB, qkvp);
  k45_dwheads <<<192, 256, 0, stream>>>(qkvp, h_qdw, v_qdw, qkvn);
  k6_attn  <<<dim3(56, 4, 2), 256, 0, stream>>>(qkvn, h_temp, v_temp, h_ca, v_ca, aoB);
  k7_mfma  <<<dim3(28, 4, 8), 256, 0, stream>>>(aoB, projB, xlf, x2);
  k8_mfma  <<<dim3(896, 2), 256, 0, stream>>>(x2, h_ge, h_be, v_ge, v_be,
                                              h_dw, v_dw, pinB, poB, gmaxU);
  k9_final <<<6272, 256, 0, stream>>>(x2, gmaxU, f1, f2, (float*)d_out);
}